// Round 9
// baseline (92.215 us; speedup 1.0000x reference)
//
#include <hip/hip_runtime.h>
#include <hip/hip_bf16.h>
#include <math.h>

#define BATCH 4096
#define DIM 128
#define TWO_B 8192
// reps scaled by sqrt(2*log2(e)) so fp8 MFMA acc = 2*log2(e)*sim, and
// exp(sim/TEMP) = exp(2*sim) = exp2(acc) -> single native v_exp_f32.
#define SCALE 1.69864374f
#define NJOBS 8320          // 65 * 32 * 4 wave-jobs (includes 32 mirror skips)
#define NWAVES 3072         // 768 blocks * 4 waves (exactly 3 blocks/CU)

typedef float floatx4 __attribute__((ext_vector_type(4)));
typedef int   intx4  __attribute__((ext_vector_type(4)));
typedef long  longx2 __attribute__((ext_vector_type(2)));

__device__ __forceinline__ longx2 as_l2(intx4 v) {
    union { intx4 a; longx2 b; } u; u.a = v; return u.b;
}
__device__ __forceinline__ unsigned char to_fp8(float v) {
    return (unsigned char)(__builtin_amdgcn_cvt_pk_fp8_f32(v, v, 0, false) & 0xff);
}

// FP8 fragment-native blocked layout (byte address):
//   addr(r,k) = (r>>4)*2048 + (k>>6)*1024 + ((k>>3)&3)*256 + (r&15)*16
//             + ((k>>5)&1)*8 + (k&7)
// A wave's 16-lane-group load at q*256 + lr*16 of 16B yields exactly the
// mfma_f32_16x16x32_fp8 A/B fragments for two K=32 chunks (1KB/instruction).

// Kernel 1: L2-normalize (pre-scaled) -> fp8 blocked reps; fp32 positives.
// LDS-staged writeback: one coalesced 4B/thread store hitting only full lines.
__global__ __launch_bounds__(256) void norm_kernel(const float* __restrict__ p1,
                                                   const float* __restrict__ p2,
                                                   unsigned char* __restrict__ repsF,
                                                   float* __restrict__ pos,
                                                   float* __restrict__ out) {
    __shared__ unsigned char stage[2][8][64];   // [proj][chunk][slot*16+inner]
    int tid = threadIdx.x;
    int w = tid >> 6, l = tid & 63;
    int b0 = blockIdx.x * 4;
    int b = b0 + w;
    const float* r1 = p1 + (size_t)b * DIM;
    const float* r2 = p2 + (size_t)b * DIM;
    float x0 = r1[l], x1 = r1[l + 64];
    float y0 = r2[l], y1 = r2[l + 64];
    float s1 = x0 * x0 + x1 * x1;
    float s2 = y0 * y0 + y1 * y1;
    float s12 = x0 * y0 + x1 * y1;
    #pragma unroll
    for (int off = 32; off; off >>= 1) {
        s1  += __shfl_xor(s1, off);
        s2  += __shfl_xor(s2, off);
        s12 += __shfl_xor(s12, off);
    }
    float n1 = fmaxf(sqrtf(s1), 1e-12f);
    float n2 = fmaxf(sqrtf(s2), 1e-12f);
    float i1 = SCALE / n1;
    float i2 = SCALE / n2;

    int cc = (l >> 3) & 3;
    int inner = ((l >> 5) & 1) * 8 + (l & 7);
    stage[0][cc    ][w * 16 + inner] = to_fp8(x0 * i1);
    stage[0][cc + 4][w * 16 + inner] = to_fp8(x1 * i1);
    stage[1][cc    ][w * 16 + inner] = to_fp8(y0 * i2);
    stage[1][cc + 4][w * 16 + inner] = to_fp8(y1 * i2);

    if (l == 0) {
        pos[b] = s12 / (n1 * n2);            // exact fp32 positive (unscaled)
        if (b == 0) out[0] = 0.0f;
    }
    __syncthreads();

    int which = tid >> 7, u = tid & 127;
    int ch = u >> 4, l16 = u & 15;
    int rowbase = which ? (b0 + BATCH) : b0;
    size_t gbyte = (size_t)(rowbase >> 4) * 2048 + ch * 256 + (b0 & 15) * 16 + l16 * 4;
    *(int*)(repsF + gbyte) = ((const int*)&stage[which][ch][0])[l16];
}

__device__ __forceinline__ void decode_job(int j, int& tm, int& tn, bool& skip) {
    // j = c*128 + r*4 + wid ; c in [0,65), r in [0,32), wid in [0,4)
    int c = j >> 7, r = (j >> 2) & 31, wid = j & 3;
    int wm = wid >> 1, wn = wid & 1;
    int TM, TN;
    if (c < 64 - r) { TM = r;      TN = r + c; }
    else            { TM = 63 - r; TN = TM + (c - (64 - r)); }
    skip = (TM == TN) && (wm == 1) && (wn == 0);   // mirror quadrant
    tm = 2 * TM + wm;                              // tm <= tn guaranteed
    tn = 2 * TN + wn;
}

// Kernel 2: PERSISTENT pipelined sim. 3072 waves; each wave loops over <=3 of
// the 8320 wave-jobs (64x64 tile pair each, tm<=tn, triangular coverage).
// Per iteration: MFMA(j) -> issue fragment loads for job j+NWAVES -> epilogue(j);
// the ~1k-cycle exp/shuffle epilogue hides the next job's entire L2 burst.
// No LDS, no barriers, no atomics: part[k][r] written exactly once
// (k>=j row-parts of (j,k); k<j col-parts of (k,j); k==j diag row-part).
__global__ __launch_bounds__(256, 3) void sim_kernel(const unsigned char* __restrict__ repsF,
                                                     float* __restrict__ part) {
    int tid = threadIdx.x;
    int lane = tid & 63;
    int w = blockIdx.x * 4 + (tid >> 6);       // wave-job id [0, NWAVES)
    int lr = lane & 15, q = lane >> 4;
    int lofs = q * 256 + lr * 16;
    const char* base = (const char*)repsF;

    int tm, tn; bool skip;
    decode_job(w, tm, tn, skip);

    longx2 aF[4][2], bF[4][2];                 // [mi][h]: .x = chunk 2h, .y = 2h+1
    {
        const char* ab = base + tm * 8192 + lofs;
        const char* bb = base + tn * 8192 + lofs;
        #pragma unroll
        for (int mi = 0; mi < 4; ++mi)
            #pragma unroll
            for (int h = 0; h < 2; ++h) {
                aF[mi][h] = as_l2(*(const intx4*)(ab + mi * 2048 + h * 1024));
                bF[mi][h] = as_l2(*(const intx4*)(bb + mi * 2048 + h * 1024));
            }
    }

    #pragma unroll 1
    for (int j = w; j < NJOBS; j += NWAVES) {
        int tmc = tm, tnc = tn;
        bool skipc = skip;
        bool diag = (tmc == tnc);

        floatx4 acc[4][4] = {};
        #pragma unroll
        for (int ck = 0; ck < 4; ++ck) {       // K=32 chunks
            int h = ck >> 1, sel = ck & 1;
            #pragma unroll
            for (int mi = 0; mi < 4; ++mi)
                #pragma unroll
                for (int ni = 0; ni < 4; ++ni)
                    acc[mi][ni] = __builtin_amdgcn_mfma_f32_16x16x32_fp8_fp8(
                        aF[mi][h][sel], bF[ni][h][sel], acc[mi][ni], 0, 0, 0);
        }

        // Prefetch next job's fragments; epilogue below hides the latency.
        int jn = j + NWAVES;
        if (jn < NJOBS) {
            decode_job(jn, tm, tn, skip);
            const char* ab = base + tm * 8192 + lofs;
            const char* bb = base + tn * 8192 + lofs;
            #pragma unroll
            for (int mi = 0; mi < 4; ++mi)
                #pragma unroll
                for (int h = 0; h < 2; ++h) {
                    aF[mi][h] = as_l2(*(const intx4*)(ab + mi * 2048 + h * 1024));
                    bF[mi][h] = as_l2(*(const intx4*)(bb + mi * 2048 + h * 1024));
                }
        }

        if (skipc) continue;

        // Epilogue. C/D layout: col = lr + 16*ni, row = q*4 + reg + 16*mi.
        float cs[4] = {0.0f, 0.0f, 0.0f, 0.0f};
        #pragma unroll
        for (int mi = 0; mi < 4; ++mi) {
            float rp[4];
            #pragma unroll
            for (int reg = 0; reg < 4; ++reg) {
                float e0 = __builtin_amdgcn_exp2f(acc[mi][0][reg]);
                float e1 = __builtin_amdgcn_exp2f(acc[mi][1][reg]);
                float e2 = __builtin_amdgcn_exp2f(acc[mi][2][reg]);
                float e3 = __builtin_amdgcn_exp2f(acc[mi][3][reg]);
                if (diag && (q * 4 + reg) == lr) {
                    if (mi == 0) e0 = 0.0f;
                    if (mi == 1) e1 = 0.0f;
                    if (mi == 2) e2 = 0.0f;
                    if (mi == 3) e3 = 0.0f;
                }
                cs[0] += e0; cs[1] += e1; cs[2] += e2; cs[3] += e3;
                rp[reg] = (e0 + e1) + (e2 + e3);
            }
            #pragma unroll
            for (int mask = 1; mask < 16; mask <<= 1)
                #pragma unroll
                for (int reg = 0; reg < 4; ++reg)
                    rp[reg] += __shfl_xor(rp[reg], mask);
            if (lr == 0) {
                #pragma unroll
                for (int reg = 0; reg < 4; ++reg)
                    part[(size_t)tnc * TWO_B + tmc * 64 + mi * 16 + q * 4 + reg] =
                        rp[reg];
            }
        }
        if (!diag) {
            #pragma unroll
            for (int ni = 0; ni < 4; ++ni) {
                cs[ni] += __shfl_xor(cs[ni], 16);
                cs[ni] += __shfl_xor(cs[ni], 32);
            }
            if (q == 0) {
                #pragma unroll
                for (int ni = 0; ni < 4; ++ni)
                    part[(size_t)tmc * TWO_B + tnc * 64 + ni * 16 + lr] = cs[ni];
            }
        }
    }
}

// Kernel 3: denom[r] = sum_k part[k][r]; loss = mean(log(denom) - 2*pos).
__global__ __launch_bounds__(128) void reduce_kernel(const float* __restrict__ part,
                                                     const float* __restrict__ pos,
                                                     float* __restrict__ out) {
    int tid = threadIdx.x;
    int rr = blockIdx.x * 128 + tid;
    float s0 = 0.0f, s1 = 0.0f, s2 = 0.0f, s3 = 0.0f;
    #pragma unroll 8
    for (int k = 0; k < 128; k += 4) {
        s0 += part[(size_t)(k + 0) * TWO_B + rr];
        s1 += part[(size_t)(k + 1) * TWO_B + rr];
        s2 += part[(size_t)(k + 2) * TWO_B + rr];
        s3 += part[(size_t)(k + 3) * TWO_B + rr];
    }
    float v = __logf((s0 + s1) + (s2 + s3)) - 2.0f * pos[rr & (BATCH - 1)];
    #pragma unroll
    for (int off = 32; off; off >>= 1) v += __shfl_xor(v, off);
    __shared__ float sred[2];
    int lane = tid & 63, wid = tid >> 6;
    if (lane == 0) sred[wid] = v;
    __syncthreads();
    if (tid == 0)
        atomicAdd(out, (sred[0] + sred[1]) * (1.0f / TWO_B));
}

extern "C" void kernel_launch(void* const* d_in, const int* in_sizes, int n_in,
                              void* d_out, int out_size, void* d_ws, size_t ws_size,
                              hipStream_t stream) {
    const float* p1 = (const float*)d_in[0];
    const float* p2 = (const float*)d_in[1];
    float* out = (float*)d_out;

    char* ws = (char*)d_ws;
    unsigned char* repsF = (unsigned char*)ws;                 // 1 MB
    float* pos  = (float*)(ws + (size_t)TWO_B * DIM);          // 16 KB
    float* part = pos + BATCH;                                 // 4 MB

    norm_kernel<<<BATCH / 4, 256, 0, stream>>>(p1, p2, repsF, pos, out);
    sim_kernel<<<NWAVES / 4, 256, 0, stream>>>(repsF, part);
    reduce_kernel<<<TWO_B / 128, 128, 0, stream>>>(part, pos, out);
}

// Round 10
// 77.982 us; speedup vs baseline: 1.1825x; 1.1825x over previous
//
#include <hip/hip_runtime.h>
#include <hip/hip_bf16.h>
#include <math.h>

#define BATCH 4096
#define DIM 128
#define TWO_B 8192
// reps scaled by sqrt(2*log2(e)) so fp8 MFMA acc = 2*log2(e)*sim, and
// exp(sim/TEMP) = exp(2*sim) = exp2(acc) -> single native v_exp_f32.
#define SCALE 1.69864374f

typedef float floatx4 __attribute__((ext_vector_type(4)));
typedef int   intx4  __attribute__((ext_vector_type(4)));
typedef long  longx2 __attribute__((ext_vector_type(2)));

__device__ __forceinline__ longx2 as_l2(intx4 v) {
    union { intx4 a; longx2 b; } u; u.a = v; return u.b;
}
__device__ __forceinline__ unsigned char to_fp8(float v) {
    return (unsigned char)(__builtin_amdgcn_cvt_pk_fp8_f32(v, v, 0, false) & 0xff);
}

// FP8 fragment-native blocked layout (byte address):
//   addr(r,k) = (r>>4)*2048 + (k>>6)*1024 + ((k>>3)&3)*256 + (r&15)*16
//             + ((k>>5)&1)*8 + (k&7)
// A wave's 16-lane-group load at q*256 + lr*16 of 16B yields exactly the
// mfma_f32_16x16x32_fp8 A/B fragments for two K=32 chunks (1KB/instruction).

// Kernel 1: L2-normalize (pre-scaled) -> fp8 blocked reps; fp32 positives.
// (R7-exact: best measured variant.)
__global__ __launch_bounds__(256) void norm_kernel(const float* __restrict__ p1,
                                                   const float* __restrict__ p2,
                                                   unsigned char* __restrict__ repsF,
                                                   float* __restrict__ pos,
                                                   float* __restrict__ out) {
    int tid = threadIdx.x;
    int w = tid >> 6, l = tid & 63;
    int b = blockIdx.x * 4 + w;
    const float* r1 = p1 + (size_t)b * DIM;
    const float* r2 = p2 + (size_t)b * DIM;
    float x0 = r1[l], x1 = r1[l + 64];
    float y0 = r2[l], y1 = r2[l + 64];
    float s1 = x0 * x0 + x1 * x1;
    float s2 = y0 * y0 + y1 * y1;
    float s12 = x0 * y0 + x1 * y1;
    #pragma unroll
    for (int off = 32; off; off >>= 1) {
        s1  += __shfl_xor(s1, off);
        s2  += __shfl_xor(s2, off);
        s12 += __shfl_xor(s12, off);
    }
    float n1 = fmaxf(sqrtf(s1), 1e-12f);
    float n2 = fmaxf(sqrtf(s2), 1e-12f);
    float i1 = SCALE / n1;
    float i2 = SCALE / n2;

    int r1i = b, r2i = b + BATCH;
    int off0 = ((l >> 5) & 1) * 8 + ((l >> 3) & 3) * 256 + (l & 7);  // k = l (h=0)
    size_t a1 = (size_t)(r1i >> 4) * 2048 + (r1i & 15) * 16 + off0;
    size_t a2 = (size_t)(r2i >> 4) * 2048 + (r2i & 15) * 16 + off0;
    repsF[a1]        = to_fp8(x0 * i1);      // k = l
    repsF[a1 + 1024] = to_fp8(x1 * i1);      // k = l + 64 (h=1)
    repsF[a2]        = to_fp8(y0 * i2);
    repsF[a2 + 1024] = to_fp8(y1 * i2);

    if (l == 0) {
        pos[b] = s12 / (n1 * n2);            // exact fp32 positive (unscaled)
        if (b == 0) out[0] = 0.0f;
    }
}

// Kernel 2: 128x128 pair-region per block, triangular TM<=TN (grid 65x32,
// zero idle). 4 waves 2x2; wave (wm,wn) owns 64x64 tile pair (tm<=tn);
// mirror quadrant of diag region skipped. All-K fp8 fragments resident,
// single MFMA pass, bare-exp2 epilogue. (R7-exact: best measured variant.)
// No LDS, no barriers, no atomics: part[k][r] written exactly once
// (k>=j row-parts of (j,k); k<j col-parts of (k,j); k==j diag row-part).
__global__ __launch_bounds__(256, 3) void sim_kernel(const unsigned char* __restrict__ repsF,
                                                     float* __restrict__ part) {
    int tid = threadIdx.x;
    int wid = tid >> 6, lane = tid & 63;
    int wm = wid >> 1, wn = wid & 1;
    int lr = lane & 15, q = lane >> 4;
    int r = blockIdx.y;                  // [0,32)
    int c = blockIdx.x;                  // [0,65)
    int TM, TN;
    if (c < 64 - r) { TM = r;      TN = r + c; }
    else            { TM = 63 - r; TN = TM + (c - (64 - r)); }
    if (TM == TN && wm == 1 && wn == 0) return;   // mirror quadrant
    int tm = 2 * TM + wm, tn = 2 * TN + wn;       // tm <= tn guaranteed
    bool diag = (tm == tn);

    const char* base = (const char*)repsF;
    int lofs = q * 256 + lr * 16;
    const char* ab = base + tm * 8192 + lofs;
    const char* bb = base + tn * 8192 + lofs;

    longx2 aF[4][2], bF[4][2];           // [mi][h]: .x = chunk 2h, .y = 2h+1
    #pragma unroll
    for (int mi = 0; mi < 4; ++mi)
        #pragma unroll
        for (int h = 0; h < 2; ++h) {
            aF[mi][h] = as_l2(*(const intx4*)(ab + mi * 2048 + h * 1024));
            bF[mi][h] = as_l2(*(const intx4*)(bb + mi * 2048 + h * 1024));
        }

    floatx4 acc[4][4] = {};
    #pragma unroll
    for (int ck = 0; ck < 4; ++ck) {     // K=32 chunks
        int h = ck >> 1, sel = ck & 1;
        #pragma unroll
        for (int mi = 0; mi < 4; ++mi)
            #pragma unroll
            for (int ni = 0; ni < 4; ++ni)
                acc[mi][ni] = __builtin_amdgcn_mfma_f32_16x16x32_fp8_fp8(
                    aF[mi][h][sel], bF[ni][h][sel], acc[mi][ni], 0, 0, 0);
    }

    // Epilogue. C/D layout: col = lr + 16*ni, row = q*4 + reg + 16*mi.
    float cs[4] = {0.0f, 0.0f, 0.0f, 0.0f};
    #pragma unroll
    for (int mi = 0; mi < 4; ++mi) {
        float rp[4];
        #pragma unroll
        for (int reg = 0; reg < 4; ++reg) {
            float e0 = __builtin_amdgcn_exp2f(acc[mi][0][reg]);
            float e1 = __builtin_amdgcn_exp2f(acc[mi][1][reg]);
            float e2 = __builtin_amdgcn_exp2f(acc[mi][2][reg]);
            float e3 = __builtin_amdgcn_exp2f(acc[mi][3][reg]);
            if (diag && (q * 4 + reg) == lr) {
                if (mi == 0) e0 = 0.0f;
                if (mi == 1) e1 = 0.0f;
                if (mi == 2) e2 = 0.0f;
                if (mi == 3) e3 = 0.0f;
            }
            cs[0] += e0; cs[1] += e1; cs[2] += e2; cs[3] += e3;
            rp[reg] = (e0 + e1) + (e2 + e3);
        }
        #pragma unroll
        for (int mask = 1; mask < 16; mask <<= 1)
            #pragma unroll
            for (int reg = 0; reg < 4; ++reg)
                rp[reg] += __shfl_xor(rp[reg], mask);
        if (lr == 0) {
            #pragma unroll
            for (int reg = 0; reg < 4; ++reg)
                part[(size_t)tn * TWO_B + tm * 64 + mi * 16 + q * 4 + reg] = rp[reg];
        }
    }
    if (!diag) {
        #pragma unroll
        for (int ni = 0; ni < 4; ++ni) {
            cs[ni] += __shfl_xor(cs[ni], 16);
            cs[ni] += __shfl_xor(cs[ni], 32);
        }
        if (q == 0) {
            #pragma unroll
            for (int ni = 0; ni < 4; ++ni)
                part[(size_t)tm * TWO_B + tn * 64 + ni * 16 + lr] = cs[ni];
        }
    }
}

// Kernel 3 (REDESIGNED): denom[r] = sum_k part[k][r]; loss contribution.
// 128 blocks x 256 threads; each block owns 64 rows, the 128 k-slots split
// across the 4 waves (32 fully-INDEPENDENT loads per thread -> one latency
// exposure instead of a 32-deep serial chain), LDS-combined, then log/sum.
__global__ __launch_bounds__(256) void reduce_kernel(const float* __restrict__ part,
                                                     const float* __restrict__ pos,
                                                     float* __restrict__ out) {
    __shared__ float stage[4][64];
    int tid = threadIdx.x;
    int w = tid >> 6, l = tid & 63;
    int rr = blockIdx.x * 64 + l;
    const float* p = part + (size_t)(w * 32) * TWO_B + rr;
    float s0 = 0.0f, s1 = 0.0f, s2 = 0.0f, s3 = 0.0f;
    #pragma unroll
    for (int k = 0; k < 32; k += 4) {       // 32 independent loads, 4 accumulators
        s0 += p[(size_t)(k + 0) * TWO_B];
        s1 += p[(size_t)(k + 1) * TWO_B];
        s2 += p[(size_t)(k + 2) * TWO_B];
        s3 += p[(size_t)(k + 3) * TWO_B];
    }
    stage[w][l] = (s0 + s1) + (s2 + s3);
    __syncthreads();
    if (w == 0) {
        float s = (stage[0][l] + stage[1][l]) + (stage[2][l] + stage[3][l]);
        float v = __logf(s) - 2.0f * pos[rr & (BATCH - 1)];
        #pragma unroll
        for (int off = 32; off; off >>= 1) v += __shfl_xor(v, off);
        if (l == 0) atomicAdd(out, v * (1.0f / TWO_B));
    }
}

extern "C" void kernel_launch(void* const* d_in, const int* in_sizes, int n_in,
                              void* d_out, int out_size, void* d_ws, size_t ws_size,
                              hipStream_t stream) {
    const float* p1 = (const float*)d_in[0];
    const float* p2 = (const float*)d_in[1];
    float* out = (float*)d_out;

    char* ws = (char*)d_ws;
    unsigned char* repsF = (unsigned char*)ws;                 // 1 MB
    float* pos  = (float*)(ws + (size_t)TWO_B * DIM);          // 16 KB
    float* part = pos + BATCH;                                 // 4 MB

    norm_kernel<<<BATCH / 4, 256, 0, stream>>>(p1, p2, repsF, pos, out);
    sim_kernel<<<dim3(65, 32), 256, 0, stream>>>(repsF, part);
    reduce_kernel<<<TWO_B / 64, 256, 0, stream>>>(part, pos, out);
}

// Round 11
// 73.256 us; speedup vs baseline: 1.2588x; 1.0645x over previous
//
#include <hip/hip_runtime.h>
#include <hip/hip_bf16.h>
#include <math.h>

#define BATCH 4096
#define DIM 128
#define TWO_B 8192
// reps scaled by sqrt(2*log2(e)) so fp8 MFMA acc = 2*log2(e)*sim, and
// exp(sim/TEMP) = exp(2*sim) = exp2(acc) -> single native v_exp_f32.
#define SCALE 1.69864374f

typedef float floatx4 __attribute__((ext_vector_type(4)));
typedef int   intx4  __attribute__((ext_vector_type(4)));
typedef long  longx2 __attribute__((ext_vector_type(2)));

__device__ __forceinline__ longx2 as_l2(intx4 v) {
    union { intx4 a; longx2 b; } u; u.a = v; return u.b;
}
__device__ __forceinline__ unsigned char to_fp8(float v) {
    return (unsigned char)(__builtin_amdgcn_cvt_pk_fp8_f32(v, v, 0, false) & 0xff);
}

// FP8 fragment-native blocked layout (byte address):
//   addr(r,k) = (r>>4)*2048 + (k>>6)*1024 + ((k>>3)&3)*256 + (r&15)*16
//             + ((k>>5)&1)*8 + (k&7)
// A wave's 16-lane-group load at q*256 + lr*16 of 16B yields exactly the
// mfma_f32_16x16x32_fp8 A/B fragments for two K=32 chunks (1KB/instruction).

// Kernel 1: L2-normalize (pre-scaled) -> fp8 blocked reps; fp32 positives.
// (R7/R10-exact: best measured variant.)
__global__ __launch_bounds__(256) void norm_kernel(const float* __restrict__ p1,
                                                   const float* __restrict__ p2,
                                                   unsigned char* __restrict__ repsF,
                                                   float* __restrict__ pos,
                                                   float* __restrict__ out) {
    int tid = threadIdx.x;
    int w = tid >> 6, l = tid & 63;
    int b = blockIdx.x * 4 + w;
    const float* r1 = p1 + (size_t)b * DIM;
    const float* r2 = p2 + (size_t)b * DIM;
    float x0 = r1[l], x1 = r1[l + 64];
    float y0 = r2[l], y1 = r2[l + 64];
    float s1 = x0 * x0 + x1 * x1;
    float s2 = y0 * y0 + y1 * y1;
    float s12 = x0 * y0 + x1 * y1;
    #pragma unroll
    for (int off = 32; off; off >>= 1) {
        s1  += __shfl_xor(s1, off);
        s2  += __shfl_xor(s2, off);
        s12 += __shfl_xor(s12, off);
    }
    float n1 = fmaxf(sqrtf(s1), 1e-12f);
    float n2 = fmaxf(sqrtf(s2), 1e-12f);
    float i1 = SCALE / n1;
    float i2 = SCALE / n2;

    int r1i = b, r2i = b + BATCH;
    int off0 = ((l >> 5) & 1) * 8 + ((l >> 3) & 3) * 256 + (l & 7);  // k = l (h=0)
    size_t a1 = (size_t)(r1i >> 4) * 2048 + (r1i & 15) * 16 + off0;
    size_t a2 = (size_t)(r2i >> 4) * 2048 + (r2i & 15) * 16 + off0;
    repsF[a1]        = to_fp8(x0 * i1);      // k = l
    repsF[a1 + 1024] = to_fp8(x1 * i1);      // k = l + 64 (h=1)
    repsF[a2]        = to_fp8(y0 * i2);
    repsF[a2 + 1024] = to_fp8(y1 * i2);

    if (l == 0) {
        pos[b] = s12 / (n1 * n2);            // exact fp32 positive (unscaled)
        if (b == 0) out[0] = 0.0f;
    }
}

// Kernel 2: 128x128 pair-region per block, triangular TM<=TN (grid 65x32,
// zero idle). 4 waves 2x2; wave (wm,wn) owns 64x64 tile pair (tm<=tn);
// mirror quadrant of diag region skipped. All-K fp8 fragments resident,
// single MFMA pass, bare-exp2 epilogue.
// NEW (R11): row-marginal via wave-local LDS transpose instead of the
// 64-op dependent bpermute butterfly: in-lane ni-sum -> 4x ds_write_b128
// into a 68-padded [16][68] slab (8 words/bank = wave64 minimum, conflict
// free) -> 16 independent ds_read_b32 (+15 adds) -> row sums one-per-lane
// -> fully-contiguous 256B wave store. LDS-pipe ops/wave: 72 -> ~28.
// No barriers, no atomics: part[k][r] written exactly once
// (k>=j row-parts of (j,k); k<j col-parts of (k,j); k==j diag row-part).
__global__ __launch_bounds__(256, 3) void sim_kernel(const unsigned char* __restrict__ repsF,
                                                     float* __restrict__ part) {
    __shared__ float lds[4][16][68];     // per-wave transpose slab (wave-local)
    int tid = threadIdx.x;
    int wid = tid >> 6, lane = tid & 63;
    int wm = wid >> 1, wn = wid & 1;
    int lr = lane & 15, q = lane >> 4;
    int r = blockIdx.y;                  // [0,32)
    int c = blockIdx.x;                  // [0,65)
    int TM, TN;
    if (c < 64 - r) { TM = r;      TN = r + c; }
    else            { TM = 63 - r; TN = TM + (c - (64 - r)); }
    if (TM == TN && wm == 1 && wn == 0) return;   // mirror quadrant
    int tm = 2 * TM + wm, tn = 2 * TN + wn;       // tm <= tn guaranteed
    bool diag = (tm == tn);

    const char* base = (const char*)repsF;
    int lofs = q * 256 + lr * 16;
    const char* ab = base + tm * 8192 + lofs;
    const char* bb = base + tn * 8192 + lofs;

    longx2 aF[4][2], bF[4][2];           // [mi][h]: .x = chunk 2h, .y = 2h+1
    #pragma unroll
    for (int mi = 0; mi < 4; ++mi)
        #pragma unroll
        for (int h = 0; h < 2; ++h) {
            aF[mi][h] = as_l2(*(const intx4*)(ab + mi * 2048 + h * 1024));
            bF[mi][h] = as_l2(*(const intx4*)(bb + mi * 2048 + h * 1024));
        }

    floatx4 acc[4][4] = {};
    #pragma unroll
    for (int ck = 0; ck < 4; ++ck) {     // K=32 chunks
        int h = ck >> 1, sel = ck & 1;
        #pragma unroll
        for (int mi = 0; mi < 4; ++mi)
            #pragma unroll
            for (int ni = 0; ni < 4; ++ni)
                acc[mi][ni] = __builtin_amdgcn_mfma_f32_16x16x32_fp8_fp8(
                    aF[mi][h][sel], bF[ni][h][sel], acc[mi][ni], 0, 0, 0);
    }

    // Epilogue. C/D layout: col = lr + 16*ni, row = q*4 + reg + 16*mi.
    float* myl = &lds[wid][0][0];        // [16][68] floats
    float cs[4] = {0.0f, 0.0f, 0.0f, 0.0f};
    #pragma unroll
    for (int mi = 0; mi < 4; ++mi) {
        floatx4 rp;
        #pragma unroll
        for (int reg = 0; reg < 4; ++reg) {
            float e0 = __builtin_amdgcn_exp2f(acc[mi][0][reg]);
            float e1 = __builtin_amdgcn_exp2f(acc[mi][1][reg]);
            float e2 = __builtin_amdgcn_exp2f(acc[mi][2][reg]);
            float e3 = __builtin_amdgcn_exp2f(acc[mi][3][reg]);
            if (diag && (q * 4 + reg) == lr) {
                if (mi == 0) e0 = 0.0f;
                if (mi == 1) e1 = 0.0f;
                if (mi == 2) e2 = 0.0f;
                if (mi == 3) e3 = 0.0f;
            }
            cs[0] += e0; cs[1] += e1; cs[2] += e2; cs[3] += e3;
            rp[reg] = (e0 + e1) + (e2 + e3);
        }
        // rows 16*mi + 4*q + (0..3) at col-residue lr -> lds[lr][row]
        *(floatx4*)&myl[lr * 68 + mi * 16 + q * 4] = rp;
    }
    asm volatile("s_waitcnt lgkmcnt(0)" ::: "memory");   // wave-local transpose
    {
        float rs = 0.0f;
        #pragma unroll
        for (int j = 0; j < 16; ++j)
            rs += myl[j * 68 + lane];    // bank = (4j+lane)%32 -> 2-way, free
        // contiguous 256B wave store of the 64 row sums
        part[(size_t)tn * TWO_B + tm * 64 + lane] = rs;
    }
    if (!diag) {
        #pragma unroll
        for (int ni = 0; ni < 4; ++ni) {
            cs[ni] += __shfl_xor(cs[ni], 16);
            cs[ni] += __shfl_xor(cs[ni], 32);
        }
        if (q == 0) {
            #pragma unroll
            for (int ni = 0; ni < 4; ++ni)
                part[(size_t)tm * TWO_B + tn * 64 + ni * 16 + lr] = cs[ni];
        }
    }
}

// Kernel 3: denom[r] = sum_k part[k][r]; loss contribution. (R10-exact.)
// 128 blocks x 256 threads; 128 k-slots split across 4 waves (32 independent
// loads per thread -> one latency exposure), LDS-combined, then log/sum.
__global__ __launch_bounds__(256) void reduce_kernel(const float* __restrict__ part,
                                                     const float* __restrict__ pos,
                                                     float* __restrict__ out) {
    __shared__ float stage[4][64];
    int tid = threadIdx.x;
    int w = tid >> 6, l = tid & 63;
    int rr = blockIdx.x * 64 + l;
    const float* p = part + (size_t)(w * 32) * TWO_B + rr;
    float s0 = 0.0f, s1 = 0.0f, s2 = 0.0f, s3 = 0.0f;
    #pragma unroll
    for (int k = 0; k < 32; k += 4) {
        s0 += p[(size_t)(k + 0) * TWO_B];
        s1 += p[(size_t)(k + 1) * TWO_B];
        s2 += p[(size_t)(k + 2) * TWO_B];
        s3 += p[(size_t)(k + 3) * TWO_B];
    }
    stage[w][l] = (s0 + s1) + (s2 + s3);
    __syncthreads();
    if (w == 0) {
        float s = (stage[0][l] + stage[1][l]) + (stage[2][l] + stage[3][l]);
        float v = __logf(s) - 2.0f * pos[rr & (BATCH - 1)];
        #pragma unroll
        for (int off = 32; off; off >>= 1) v += __shfl_xor(v, off);
        if (l == 0) atomicAdd(out, v * (1.0f / TWO_B));
    }
}

extern "C" void kernel_launch(void* const* d_in, const int* in_sizes, int n_in,
                              void* d_out, int out_size, void* d_ws, size_t ws_size,
                              hipStream_t stream) {
    const float* p1 = (const float*)d_in[0];
    const float* p2 = (const float*)d_in[1];
    float* out = (float*)d_out;

    char* ws = (char*)d_ws;
    unsigned char* repsF = (unsigned char*)ws;                 // 1 MB
    float* pos  = (float*)(ws + (size_t)TWO_B * DIM);          // 16 KB
    float* part = pos + BATCH;                                 // 4 MB

    norm_kernel<<<BATCH / 4, 256, 0, stream>>>(p1, p2, repsF, pos, out);
    sim_kernel<<<dim3(65, 32), 256, 0, stream>>>(repsF, part);
    reduce_kernel<<<TWO_B / 64, 256, 0, stream>>>(part, pos, out);
}

// Round 12
// 72.214 us; speedup vs baseline: 1.2770x; 1.0144x over previous
//
#include <hip/hip_runtime.h>
#include <hip/hip_bf16.h>
#include <math.h>

#define BATCH 4096
#define DIM 128
#define TWO_B 8192
// reps scaled by sqrt(2*log2(e)) so fp8 MFMA acc = 2*log2(e)*sim, and
// exp(sim/TEMP) = exp(2*sim) = exp2(acc) -> single native v_exp_f32.
#define SCALE 1.69864374f

typedef float floatx4 __attribute__((ext_vector_type(4)));
typedef int   intx4  __attribute__((ext_vector_type(4)));
typedef long  longx2 __attribute__((ext_vector_type(2)));

__device__ __forceinline__ longx2 as_l2(intx4 v) {
    union { intx4 a; longx2 b; } u; u.a = v; return u.b;
}
__device__ __forceinline__ unsigned char to_fp8(float v) {
    return (unsigned char)(__builtin_amdgcn_cvt_pk_fp8_f32(v, v, 0, false) & 0xff);
}

// FP8 fragment-native blocked layout (byte address):
//   addr(r,k) = (r>>4)*2048 + (k>>6)*1024 + ((k>>3)&3)*256 + (r&15)*16
//             + ((k>>5)&1)*8 + (k&7)
// A wave's 16-lane-group load at q*256 + lr*16 of 16B yields exactly the
// mfma_f32_16x16x32_fp8 A/B fragments for two K=32 chunks (1KB/instruction).

// Kernel 1: L2-normalize (pre-scaled) -> fp8 blocked reps; fp32 positives.
// (R7/R10-exact: best measured variant.)
__global__ __launch_bounds__(256) void norm_kernel(const float* __restrict__ p1,
                                                   const float* __restrict__ p2,
                                                   unsigned char* __restrict__ repsF,
                                                   float* __restrict__ pos,
                                                   float* __restrict__ out) {
    int tid = threadIdx.x;
    int w = tid >> 6, l = tid & 63;
    int b = blockIdx.x * 4 + w;
    const float* r1 = p1 + (size_t)b * DIM;
    const float* r2 = p2 + (size_t)b * DIM;
    float x0 = r1[l], x1 = r1[l + 64];
    float y0 = r2[l], y1 = r2[l + 64];
    float s1 = x0 * x0 + x1 * x1;
    float s2 = y0 * y0 + y1 * y1;
    float s12 = x0 * y0 + x1 * y1;
    #pragma unroll
    for (int off = 32; off; off >>= 1) {
        s1  += __shfl_xor(s1, off);
        s2  += __shfl_xor(s2, off);
        s12 += __shfl_xor(s12, off);
    }
    float n1 = fmaxf(sqrtf(s1), 1e-12f);
    float n2 = fmaxf(sqrtf(s2), 1e-12f);
    float i1 = SCALE / n1;
    float i2 = SCALE / n2;

    int r1i = b, r2i = b + BATCH;
    int off0 = ((l >> 5) & 1) * 8 + ((l >> 3) & 3) * 256 + (l & 7);  // k = l (h=0)
    size_t a1 = (size_t)(r1i >> 4) * 2048 + (r1i & 15) * 16 + off0;
    size_t a2 = (size_t)(r2i >> 4) * 2048 + (r2i & 15) * 16 + off0;
    repsF[a1]        = to_fp8(x0 * i1);      // k = l
    repsF[a1 + 1024] = to_fp8(x1 * i1);      // k = l + 64 (h=1)
    repsF[a2]        = to_fp8(y0 * i2);
    repsF[a2 + 1024] = to_fp8(y1 * i2);

    if (l == 0) {
        pos[b] = s12 / (n1 * n2);            // exact fp32 positive (unscaled)
        if (b == 0) out[0] = 0.0f;
    }
}

// Kernel 2: 128x128 pair-region per block, triangular TM<=TN (grid 65x32,
// zero idle). 4 waves 2x2; wave (wm,wn) owns 64x64 tile pair (tm<=tn);
// mirror quadrant of diag region skipped.
// R12: 4 blocks/CU (__launch_bounds__(256,4)). To fit 128 VGPRs, the ni
// dimension is split into 2 passes (acc[4][2] = 32 VGPRs instead of 64);
// all 16 fragment loads still issued ONCE up-front (single latency
// exposure); row-partials carried across passes in 16 registers.
// Row-marginal via wave-local LDS transpose (R11); col-marginal via
// in-lane sums + 2 shfl. No barriers, no atomics: part[k][r] written
// exactly once (k>=j row-parts of (j,k); k<j col-parts of (k,j); k==j diag).
__global__ __launch_bounds__(256, 4) void sim_kernel(const unsigned char* __restrict__ repsF,
                                                     float* __restrict__ part) {
    __shared__ float lds[4][16][68];     // per-wave transpose slab (wave-local)
    int tid = threadIdx.x;
    int wid = tid >> 6, lane = tid & 63;
    int wm = wid >> 1, wn = wid & 1;
    int lr = lane & 15, q = lane >> 4;
    int r = blockIdx.y;                  // [0,32)
    int c = blockIdx.x;                  // [0,65)
    int TM, TN;
    if (c < 64 - r) { TM = r;      TN = r + c; }
    else            { TM = 63 - r; TN = TM + (c - (64 - r)); }
    if (TM == TN && wm == 1 && wn == 0) return;   // mirror quadrant
    int tm = 2 * TM + wm, tn = 2 * TN + wn;       // tm <= tn guaranteed
    bool diag = (tm == tn);

    const char* base = (const char*)repsF;
    int lofs = q * 256 + lr * 16;
    const char* ab = base + tm * 8192 + lofs;
    const char* bb = base + tn * 8192 + lofs;

    longx2 aF[4][2], bF[4][2];           // [idx][h]: .x = chunk 2h, .y = 2h+1
    #pragma unroll
    for (int mi = 0; mi < 4; ++mi)
        #pragma unroll
        for (int h = 0; h < 2; ++h) {
            aF[mi][h] = as_l2(*(const intx4*)(ab + mi * 2048 + h * 1024));
            bF[mi][h] = as_l2(*(const intx4*)(bb + mi * 2048 + h * 1024));
        }

    float cs[4] = {0.0f, 0.0f, 0.0f, 0.0f};
    floatx4 rpacc[4];                    // row-partials per mi, across passes

    #pragma unroll
    for (int p = 0; p < 2; ++p) {        // ni-pass: cols 32p .. 32p+31
        floatx4 acc[4][2] = {};
        #pragma unroll
        for (int ck = 0; ck < 4; ++ck) { // K=32 chunks
            int h = ck >> 1, sel = ck & 1;
            #pragma unroll
            for (int mi = 0; mi < 4; ++mi)
                #pragma unroll
                for (int nn = 0; nn < 2; ++nn)
                    acc[mi][nn] = __builtin_amdgcn_mfma_f32_16x16x32_fp8_fp8(
                        aF[mi][h][sel], bF[2 * p + nn][h][sel], acc[mi][nn], 0, 0, 0);
        }
        // Partial epilogue. C/D layout: col = lr + 16*(2p+nn), row = q*4+reg+16*mi.
        #pragma unroll
        for (int mi = 0; mi < 4; ++mi) {
            #pragma unroll
            for (int reg = 0; reg < 4; ++reg) {
                float e0 = __builtin_amdgcn_exp2f(acc[mi][0][reg]);
                float e1 = __builtin_amdgcn_exp2f(acc[mi][1][reg]);
                if (diag && (q * 4 + reg) == lr) {
                    if (mi == 2 * p)     e0 = 0.0f;   // ni == mi diagonal hit
                    if (mi == 2 * p + 1) e1 = 0.0f;
                }
                cs[2 * p]     += e0;
                cs[2 * p + 1] += e1;
                float rsum = e0 + e1;
                rpacc[mi][reg] = (p == 0) ? rsum : (rpacc[mi][reg] + rsum);
            }
        }
    }

    // Row sums: wave-local LDS transpose (conflict-free padded slab).
    float* myl = &lds[wid][0][0];        // [16][68] floats
    #pragma unroll
    for (int mi = 0; mi < 4; ++mi)
        *(floatx4*)&myl[lr * 68 + mi * 16 + q * 4] = rpacc[mi];
    asm volatile("s_waitcnt lgkmcnt(0)" ::: "memory");
    {
        float rs = 0.0f;
        #pragma unroll
        for (int j = 0; j < 16; ++j)
            rs += myl[j * 68 + lane];    // bank = (4j+lane)%32 -> 2-way, free
        part[(size_t)tn * TWO_B + tm * 64 + lane] = rs;   // contiguous 256B
    }
    if (!diag) {
        #pragma unroll
        for (int ni = 0; ni < 4; ++ni) {
            cs[ni] += __shfl_xor(cs[ni], 16);
            cs[ni] += __shfl_xor(cs[ni], 32);
        }
        if (q == 0) {
            #pragma unroll
            for (int ni = 0; ni < 4; ++ni)
                part[(size_t)tm * TWO_B + tn * 64 + ni * 16 + lr] = cs[ni];
        }
    }
}

// Kernel 3: denom[r] = sum_k part[k][r]; loss contribution. (R10-exact.)
// 128 blocks x 256 threads; 128 k-slots split across 4 waves (32 independent
// loads per thread -> one latency exposure), LDS-combined, then log/sum.
__global__ __launch_bounds__(256) void reduce_kernel(const float* __restrict__ part,
                                                     const float* __restrict__ pos,
                                                     float* __restrict__ out) {
    __shared__ float stage[4][64];
    int tid = threadIdx.x;
    int w = tid >> 6, l = tid & 63;
    int rr = blockIdx.x * 64 + l;
    const float* p = part + (size_t)(w * 32) * TWO_B + rr;
    float s0 = 0.0f, s1 = 0.0f, s2 = 0.0f, s3 = 0.0f;
    #pragma unroll
    for (int k = 0; k < 32; k += 4) {
        s0 += p[(size_t)(k + 0) * TWO_B];
        s1 += p[(size_t)(k + 1) * TWO_B];
        s2 += p[(size_t)(k + 2) * TWO_B];
        s3 += p[(size_t)(k + 3) * TWO_B];
    }
    stage[w][l] = (s0 + s1) + (s2 + s3);
    __syncthreads();
    if (w == 0) {
        float s = (stage[0][l] + stage[1][l]) + (stage[2][l] + stage[3][l]);
        float v = __logf(s) - 2.0f * pos[rr & (BATCH - 1)];
        #pragma unroll
        for (int off = 32; off; off >>= 1) v += __shfl_xor(v, off);
        if (l == 0) atomicAdd(out, v * (1.0f / TWO_B));
    }
}

extern "C" void kernel_launch(void* const* d_in, const int* in_sizes, int n_in,
                              void* d_out, int out_size, void* d_ws, size_t ws_size,
                              hipStream_t stream) {
    const float* p1 = (const float*)d_in[0];
    const float* p2 = (const float*)d_in[1];
    float* out = (float*)d_out;

    char* ws = (char*)d_ws;
    unsigned char* repsF = (unsigned char*)ws;                 // 1 MB
    float* pos  = (float*)(ws + (size_t)TWO_B * DIM);          // 16 KB
    float* part = pos + BATCH;                                 // 4 MB

    norm_kernel<<<BATCH / 4, 256, 0, stream>>>(p1, p2, repsF, pos, out);
    sim_kernel<<<dim3(65, 32), 256, 0, stream>>>(repsF, part);
    reduce_kernel<<<TWO_B / 64, 256, 0, stream>>>(part, pos, out);
}